// Round 1
// baseline (715.248 us; speedup 1.0000x reference)
//
#include <hip/hip_runtime.h>

#define NEG_SLOPE 0.2f

__device__ __forceinline__ float leaky(float v) { return v > 0.f ? v : NEG_SLOPE * v; }

// ---------------- CSR build (by dst), used by both layers ----------------

__global__ void k_count(const int* __restrict__ dstE, int E, int ET, int* __restrict__ deg) {
  int e = blockIdx.x * blockDim.x + threadIdx.x;
  if (e < ET) {
    int d = (e < E) ? dstE[e] : (e - E);   // self-loops appended
    atomicAdd(&deg[d], 1);
  }
}

// inclusive scan within 256-blocks; block sums out
__global__ void k_scanA(const int* __restrict__ deg, int n, int* __restrict__ incl,
                        int* __restrict__ bsum) {
  __shared__ int s[256];
  int i = blockIdx.x * 256 + threadIdx.x;
  int v = (i < n) ? deg[i] : 0;
  s[threadIdx.x] = v;
  __syncthreads();
  for (int d = 1; d < 256; d <<= 1) {
    int t = (threadIdx.x >= d) ? s[threadIdx.x - d] : 0;
    __syncthreads();
    s[threadIdx.x] += t;
    __syncthreads();
  }
  if (i < n) incl[i] = s[threadIdx.x];
  if (threadIdx.x == 255) bsum[blockIdx.x] = s[255];
}

// exclusive scan of block sums (nb <= 512)
__global__ void k_scanB(int* __restrict__ bsum, int nb) {
  __shared__ int s[512];
  int v = (threadIdx.x < nb) ? bsum[threadIdx.x] : 0;
  s[threadIdx.x] = v;
  __syncthreads();
  for (int d = 1; d < 512; d <<= 1) {
    int t = (threadIdx.x >= d) ? s[threadIdx.x - d] : 0;
    __syncthreads();
    s[threadIdx.x] += t;
    __syncthreads();
  }
  if (threadIdx.x < nb) bsum[threadIdx.x] = s[threadIdx.x] - v;
}

// convert to exclusive offsets, init cursors, write offs[n]=ET
__global__ void k_scanC(const int* __restrict__ deg, const int* __restrict__ bsum,
                        int n, int Etot, int* __restrict__ offs, int* __restrict__ cur) {
  int i = blockIdx.x * 256 + threadIdx.x;
  if (i < n) {
    int excl = offs[i] - deg[i] + bsum[blockIdx.x];  // offs currently holds inclusive
    offs[i] = excl;
    cur[i] = excl;
  }
  if (i == 0 && blockIdx.x == 0) offs[n] = Etot;
}

__global__ void k_fill(const int* __restrict__ ei, int E, int ET,
                       int* __restrict__ cur, int* __restrict__ csr) {
  int e = blockIdx.x * blockDim.x + threadIdx.x;
  if (e < ET) {
    int s, d;
    if (e < E) { s = ei[e]; d = ei[E + e]; }
    else       { s = e - E; d = s; }
    int pos = atomicAdd(&cur[d], 1);
    csr[pos] = s;
  }
}

// ---------------- layer math ----------------

// h = x @ W1 (512 -> 16), also alpha_s/alpha_d per node.
// 128 threads/block, 1 node per thread, x staged through LDS in [128 x 32] tiles.
__global__ __launch_bounds__(128) void k_gemm1(
    const float* __restrict__ x, const float* __restrict__ W1,
    const float* __restrict__ a_s, const float* __restrict__ a_d,
    int N, float* __restrict__ h, float* __restrict__ asv, float* __restrict__ adv) {
  __shared__ float xs[128 * 36];   // 32 floats + 4 pad per row (16B-aligned rows)
  const int tid = threadIdx.x;
  const int base = blockIdx.x * 128;
  const int node = base + tid;

  float acc[16];
#pragma unroll
  for (int j = 0; j < 16; ++j) acc[j] = 0.f;

  for (int k0 = 0; k0 < 512; k0 += 32) {
    // stage x tile: 128 rows x 32 floats, 8 float4 slots per thread
#pragma unroll
    for (int i = 0; i < 8; ++i) {
      int slot = tid + i * 128;
      int r = slot >> 3, c4 = slot & 7;
      float4 v = make_float4(0.f, 0.f, 0.f, 0.f);
      if (base + r < N)
        v = *(const float4*)(x + (size_t)(base + r) * 512 + k0 + c4 * 4);
      *(float4*)(xs + r * 36 + c4 * 4) = v;
    }
    __syncthreads();
#pragma unroll
    for (int kk4 = 0; kk4 < 8; ++kk4) {
      float4 xv = *(const float4*)(xs + tid * 36 + kk4 * 4);
      float xq[4] = {xv.x, xv.y, xv.z, xv.w};
#pragma unroll
      for (int q = 0; q < 4; ++q) {
        const float* wrow = W1 + (size_t)(k0 + kk4 * 4 + q) * 16;  // uniform address
#pragma unroll
        for (int j = 0; j < 16; ++j) acc[j] = fmaf(xq[q], wrow[j], acc[j]);
      }
    }
    __syncthreads();
  }

  if (node < N) {
    float s = 0.f, d = 0.f;
#pragma unroll
    for (int j = 0; j < 16; ++j) {
      s = fmaf(acc[j], a_s[j], s);
      d = fmaf(acc[j], a_d[j], d);
    }
    float4* hp = (float4*)(h + (size_t)node * 16);
    hp[0] = make_float4(acc[0], acc[1], acc[2], acc[3]);
    hp[1] = make_float4(acc[4], acc[5], acc[6], acc[7]);
    hp[2] = make_float4(acc[8], acc[9], acc[10], acc[11]);
    hp[3] = make_float4(acc[12], acc[13], acc[14], acc[15]);
    asv[node] = s;
    adv[node] = d;
  }
}

// h = xin @ W (16 -> 16), plus alpha_s/alpha_d. One node per thread.
__global__ void k_gemm16(const float* __restrict__ xin, const float* __restrict__ W,
                         const float* __restrict__ a_s, const float* __restrict__ a_d,
                         int N, float* __restrict__ h, float* __restrict__ asv,
                         float* __restrict__ adv) {
  int n = blockIdx.x * blockDim.x + threadIdx.x;
  if (n >= N) return;
  float xr[16];
#pragma unroll
  for (int c = 0; c < 4; ++c) ((float4*)xr)[c] = *(const float4*)(xin + (size_t)n * 16 + c * 4);
  float acc[16];
#pragma unroll
  for (int j = 0; j < 16; ++j) acc[j] = 0.f;
#pragma unroll
  for (int k = 0; k < 16; ++k) {
    const float* wrow = W + k * 16;  // uniform
#pragma unroll
    for (int j = 0; j < 16; ++j) acc[j] = fmaf(xr[k], wrow[j], acc[j]);
  }
  float s = 0.f, d = 0.f;
#pragma unroll
  for (int j = 0; j < 16; ++j) {
    s = fmaf(acc[j], a_s[j], s);
    d = fmaf(acc[j], a_d[j], d);
  }
  float4* hp = (float4*)(h + (size_t)n * 16);
  hp[0] = make_float4(acc[0], acc[1], acc[2], acc[3]);
  hp[1] = make_float4(acc[4], acc[5], acc[6], acc[7]);
  hp[2] = make_float4(acc[8], acc[9], acc[10], acc[11]);
  hp[3] = make_float4(acc[12], acc[13], acc[14], acc[15]);
  asv[n] = s;
  adv[n] = d;
}

// gather-aggregate per dst node: out = relu( (sum_e exp(l_e) h[src_e]) / (sum_e exp(l_e)) + b )
// 16 lanes per node (lane = feature j), 16 nodes per 256-thread block.
__global__ void k_agg(const float* __restrict__ h, const float* __restrict__ asv,
                      const float* __restrict__ adv, const int* __restrict__ offs,
                      const int* __restrict__ csr, const float* __restrict__ bias,
                      int N, float* __restrict__ out) {
  int tid = threadIdx.x;
  int lane = tid & 15;
  int n = blockIdx.x * 16 + (tid >> 4);
  if (n >= N) return;
  int i0 = offs[n], i1 = offs[n + 1];
  float adn = adv[n];
  float z = 0.f, acc = 0.f;
  for (int i = i0; i < i1; ++i) {
    int s = csr[i];
    float e = __expf(leaky(asv[s] + adn));
    z += e;
    acc = fmaf(e, h[(size_t)s * 16 + lane], acc);
  }
  out[(size_t)n * 16 + lane] = fmaxf(acc / z + bias[lane], 0.f);
}

// logits = g @ Wout + bout, row-softmax, one node per thread
__global__ void k_out(const float* __restrict__ g, const float* __restrict__ Wout,
                      const float* __restrict__ bout, int N, float* __restrict__ out) {
  int n = blockIdx.x * blockDim.x + threadIdx.x;
  if (n >= N) return;
  float xr[16];
#pragma unroll
  for (int c = 0; c < 4; ++c) ((float4*)xr)[c] = *(const float4*)(g + (size_t)n * 16 + c * 4);
  float lg[16];
#pragma unroll
  for (int c = 0; c < 16; ++c) lg[c] = bout[c];
#pragma unroll
  for (int k = 0; k < 16; ++k) {
    const float* wrow = Wout + k * 16;  // uniform
#pragma unroll
    for (int c = 0; c < 16; ++c) lg[c] = fmaf(xr[k], wrow[c], lg[c]);
  }
  float m = lg[0];
#pragma unroll
  for (int c = 1; c < 16; ++c) m = fmaxf(m, lg[c]);
  float e[16];
  float zs = 0.f;
#pragma unroll
  for (int c = 0; c < 16; ++c) { e[c] = __expf(lg[c] - m); zs += e[c]; }
  float inv = 1.f / zs;
  float4* op = (float4*)(out + (size_t)n * 16);
  op[0] = make_float4(e[0] * inv, e[1] * inv, e[2] * inv, e[3] * inv);
  op[1] = make_float4(e[4] * inv, e[5] * inv, e[6] * inv, e[7] * inv);
  op[2] = make_float4(e[8] * inv, e[9] * inv, e[10] * inv, e[11] * inv);
  op[3] = make_float4(e[12] * inv, e[13] * inv, e[14] * inv, e[15] * inv);
}

// ---------------- launch ----------------

extern "C" void kernel_launch(void* const* d_in, const int* in_sizes, int n_in,
                              void* d_out, int out_size, void* d_ws, size_t ws_size,
                              hipStream_t stream) {
  const float* x    = (const float*)d_in[0];
  const float* W1   = (const float*)d_in[1];
  const float* as1  = (const float*)d_in[2];
  const float* ad1  = (const float*)d_in[3];
  const float* b1   = (const float*)d_in[4];
  const float* W2   = (const float*)d_in[5];
  const float* as2  = (const float*)d_in[6];
  const float* ad2  = (const float*)d_in[7];
  const float* b2   = (const float*)d_in[8];
  const float* Wout = (const float*)d_in[9];
  const float* bout = (const float*)d_in[10];
  const int*   ei   = (const int*)d_in[11];

  const int N  = in_sizes[0] / 512;
  const int E  = in_sizes[11] / 2;
  const int ET = E + N;
  float* out = (float*)d_out;

  // workspace carve-up
  char* w = (char*)d_ws;
  auto alloc = [&](size_t bytes) {
    char* p = w;
    w += (bytes + 255) & ~(size_t)255;
    return p;
  };
  float* h1   = (float*)alloc((size_t)N * 16 * 4);
  float* x2   = (float*)alloc((size_t)N * 16 * 4);
  float* h2   = (float*)alloc((size_t)N * 16 * 4);
  float* g    = (float*)alloc((size_t)N * 16 * 4);
  float* asv1 = (float*)alloc((size_t)N * 4);
  float* adv1 = (float*)alloc((size_t)N * 4);
  float* asv2 = (float*)alloc((size_t)N * 4);
  float* adv2 = (float*)alloc((size_t)N * 4);
  int* deg  = (int*)alloc((size_t)N * 4);
  int* offs = (int*)alloc((size_t)(N + 1) * 4);
  int* cur  = (int*)alloc((size_t)N * 4);
  int* bsum = (int*)alloc(512 * 4);
  int* csr  = (int*)alloc((size_t)ET * 4);

  const int NB256 = (N + 255) / 256;
  const int NB128 = (N + 127) / 128;
  const int EB    = (ET + 255) / 256;

  // CSR build
  hipMemsetAsync(deg, 0, (size_t)N * 4, stream);
  k_count<<<EB, 256, 0, stream>>>(ei + E, E, ET, deg);
  k_scanA<<<NB256, 256, 0, stream>>>(deg, N, offs, bsum);
  k_scanB<<<1, 512, 0, stream>>>(bsum, NB256);
  k_scanC<<<NB256, 256, 0, stream>>>(deg, bsum, N, ET, offs, cur);
  k_fill<<<EB, 256, 0, stream>>>(ei, E, ET, cur, csr);

  // layer 1
  k_gemm1<<<NB128, 128, 0, stream>>>(x, W1, as1, ad1, N, h1, asv1, adv1);
  k_agg<<<(N + 15) / 16, 256, 0, stream>>>(h1, asv1, adv1, offs, csr, b1, N, x2);

  // layer 2
  k_gemm16<<<NB256, 256, 0, stream>>>(x2, W2, as2, ad2, N, h2, asv2, adv2);
  k_agg<<<(N + 15) / 16, 256, 0, stream>>>(h2, asv2, adv2, offs, csr, b2, N, g);

  // output head
  k_out<<<NB256, 256, 0, stream>>>(g, Wout, bout, N, out);
}